// Round 1
// baseline (217.334 us; speedup 1.0000x reference)
//
#include <hip/hip_runtime.h>

#define IMG_B 32
#define IMG_HW (512 * 512)
#define NBINS 256
#define BLOCKS_PER_IMG 16
#define NTHREADS 256
#define CHUNK (IMG_HW / BLOCKS_PER_IMG)   // 16384 pixels per block
#define NWAVES (NTHREADS / 64)

// ---------------------------------------------------------------------------
// Kernel 1: per-image histogram (S = sum of luma values per bin, C = counts).
// Grid: IMG_B * BLOCKS_PER_IMG blocks, 256 threads.
// Per-wave privatized LDS histograms -> block reduce -> global atomicAdd into
// ws[img*512 + bin] (S) and ws[img*512 + 256 + bin] (C).
// ---------------------------------------------------------------------------
__global__ __launch_bounds__(NTHREADS)
void ie_hist_kernel(const float* __restrict__ x, float* __restrict__ ws) {
    __shared__ float sS[NWAVES][NBINS];
    __shared__ float sC[NWAVES][NBINS];

    const int tid  = threadIdx.x;
    const int wave = tid >> 6;
    const int blk  = blockIdx.x;
    const int img  = blk / BLOCKS_PER_IMG;
    const int part = blk % BLOCKS_PER_IMG;

    // zero LDS histograms
    for (int i = tid; i < NWAVES * NBINS; i += NTHREADS) {
        (&sS[0][0])[i] = 0.0f;
        (&sC[0][0])[i] = 0.0f;
    }
    __syncthreads();

    const float* base = x + (size_t)img * 3u * IMG_HW + (size_t)part * CHUNK;
    const float4* r4 = (const float4*)(base);
    const float4* g4 = (const float4*)(base + IMG_HW);
    const float4* b4 = (const float4*)(base + 2 * IMG_HW);

    const float interval = 1.0f / 255.0f;
    const float eps = 0.5f * interval;

    const int nvec = CHUNK / 4;  // 4096 float4 per channel
    for (int i = tid; i < nvec; i += NTHREADS) {
        float4 r = r4[i];
        float4 g = g4[i];
        float4 b = b4[i];
        float ys[4];
        ys[0] = 0.257f * r.x + 0.564f * g.x + 0.098f * b.x + 0.0625f;
        ys[1] = 0.257f * r.y + 0.564f * g.y + 0.098f * b.y + 0.0625f;
        ys[2] = 0.257f * r.z + 0.564f * g.z + 0.098f * b.z + 0.0625f;
        ys[3] = 0.257f * r.w + 0.564f * g.w + 0.098f * b.w + 0.0625f;
#pragma unroll
        for (int k = 0; k < 4; ++k) {
            float y = ys[k];
            float fidx = rintf(y * 255.0f);     // round-half-to-even, matches jnp.round
            int idx = (int)fidx;
            float v = fidx * interval;
            bool inb = (y > v - eps) && (y < v + eps) && (idx >= 0) && (idx <= NBINS - 1);
            if (inb) {
                atomicAdd(&sS[wave][idx], y);
                atomicAdd(&sC[wave][idx], 1.0f);
            }
        }
    }
    __syncthreads();

    float* gS = ws + (size_t)img * (2 * NBINS);
    float* gC = gS + NBINS;
    for (int bin = tid; bin < NBINS; bin += NTHREADS) {
        float s = 0.0f, c = 0.0f;
#pragma unroll
        for (int w = 0; w < NWAVES; ++w) {
            s += sS[w][bin];
            c += sC[w][bin];
        }
        if (c != 0.0f) {
            atomicAdd(&gS[bin], s);
            atomicAdd(&gC[bin], c);
        }
    }
}

// ---------------------------------------------------------------------------
// Kernel 2: entropy from per-image histograms. Single block, 256 threads
// (thread t owns bin t). Faithful to the reference arithmetic:
//   S[0] += N;  valid = cnt >= 1;  pixel = S/cnt;  H = S/(pixel*N);
//   entropy = sum_valid -H*log2(H);  out = sign * mean_over_images(entropy)
// ---------------------------------------------------------------------------
__global__ __launch_bounds__(NTHREADS)
void ie_entropy_kernel(const float* __restrict__ ws, const int* __restrict__ sign,
                       float* __restrict__ out) {
    const int tid = threadIdx.x;
    const float Nf = (float)IMG_HW;
    float acc = 0.0f;

    for (int img = 0; img < IMG_B; ++img) {
        float S = ws[(size_t)img * (2 * NBINS) + tid];
        float C = ws[(size_t)img * (2 * NBINS) + NBINS + tid];
        if (tid == 0) S += Nf;   // offset=1 for bin 0, added to every pixel -> +N
        if (C >= 1.0f) {
            float pixel = S / C;                 // detached mean pixel value
            float H = S / (pixel * Nf);          // == C/N in value
            acc += -H * log2f(H);
        }
    }

    // block reduction: wave shuffle then cross-wave via LDS
    __shared__ float red[NWAVES];
#pragma unroll
    for (int off = 32; off > 0; off >>= 1)
        acc += __shfl_down(acc, off, 64);
    if ((tid & 63) == 0) red[tid >> 6] = acc;
    __syncthreads();
    if (tid == 0) {
        float tot = 0.0f;
#pragma unroll
        for (int w = 0; w < NWAVES; ++w) tot += red[w];
        out[0] = (float)sign[0] * (tot / (float)IMG_B);
    }
}

extern "C" void kernel_launch(void* const* d_in, const int* in_sizes, int n_in,
                              void* d_out, int out_size, void* d_ws, size_t ws_size,
                              hipStream_t stream) {
    const float* x   = (const float*)d_in[0];
    const int* sign  = (const int*)d_in[1];
    float* out       = (float*)d_out;
    float* ws        = (float*)d_ws;

    // zero the per-image histogram workspace (ws is poisoned 0xAA each call)
    hipMemsetAsync(d_ws, 0, (size_t)IMG_B * 2 * NBINS * sizeof(float), stream);

    ie_hist_kernel<<<IMG_B * BLOCKS_PER_IMG, NTHREADS, 0, stream>>>(x, ws);
    ie_entropy_kernel<<<1, NTHREADS, 0, stream>>>(ws, sign, out);
}

// Round 2
// 165.680 us; speedup vs baseline: 1.3118x; 1.3118x over previous
//
#include <hip/hip_runtime.h>

#define IMG_B 32
#define IMG_HW (512 * 512)
#define NBINS 256
#define BPI 64                       // blocks per image
#define NTHREADS 256
#define CHUNK (IMG_HW / BPI)         // 4096 pixels per block
#define NWAVES (NTHREADS / 64)

// ---------------------------------------------------------------------------
// Kernel 1: per-block 256-bin count histogram. Counts only — the reference's
// H = S/(pixel*N) with pixel = detach(S/cnt) equals cnt/N to ~1 ulp, and the
// bin-0 "+N" offset is dead (y >= 0.0625 -> idx >= 16 -> cnt[0] == 0 always).
// Per-wave privatized LDS uint histograms (native ds_add_u32, no CAS loop),
// block-reduce, plain coalesced store to ws[blk*256 + bin]. No global atomics,
// no pre-zeroed workspace needed.
// Grid: IMG_B*BPI = 2048 blocks x 256 thr = 8 blocks/CU = 32 waves/CU.
// ---------------------------------------------------------------------------
__global__ __launch_bounds__(NTHREADS)
void ie_hist_kernel(const float* __restrict__ x, unsigned* __restrict__ ws) {
    __shared__ unsigned h[NWAVES][NBINS];

    const int tid  = threadIdx.x;
    const int wave = tid >> 6;
    const int blk  = blockIdx.x;
    const int img  = blk / BPI;
    const int part = blk % BPI;

    for (int i = tid; i < NWAVES * NBINS; i += NTHREADS)
        (&h[0][0])[i] = 0u;
    __syncthreads();

    const float* base = x + (size_t)img * 3u * IMG_HW + (size_t)part * CHUNK;
    const float4* r4 = (const float4*)(base);
    const float4* g4 = (const float4*)(base + IMG_HW);
    const float4* b4 = (const float4*)(base + 2 * IMG_HW);

    const float interval = 1.0f / 255.0f;
    const float eps = 0.5f * interval;

    const int nvec = CHUNK / 4;  // 1024 float4 per channel
    for (int i = tid; i < nvec; i += NTHREADS) {
        float4 r = r4[i];
        float4 g = g4[i];
        float4 b = b4[i];
        float ys[4];
        ys[0] = 0.257f * r.x + 0.564f * g.x + 0.098f * b.x + 0.0625f;
        ys[1] = 0.257f * r.y + 0.564f * g.y + 0.098f * b.y + 0.0625f;
        ys[2] = 0.257f * r.z + 0.564f * g.z + 0.098f * b.z + 0.0625f;
        ys[3] = 0.257f * r.w + 0.564f * g.w + 0.098f * b.w + 0.0625f;
#pragma unroll
        for (int k = 0; k < 4; ++k) {
            float y = ys[k];
            float fidx = rintf(y * 255.0f);     // round-half-to-even == jnp.round
            int idx = (int)fidx;
            float v = fidx * interval;
            bool inb = (y > v - eps) && (y < v + eps) && (idx >= 0) && (idx <= NBINS - 1);
            if (inb) atomicAdd(&h[wave][idx], 1u);
        }
    }
    __syncthreads();

    unsigned c = 0;
#pragma unroll
    for (int w = 0; w < NWAVES; ++w) c += h[w][tid];
    ws[(size_t)blk * NBINS + tid] = c;
}

// ---------------------------------------------------------------------------
// Kernel 2: entropy. Since total = sum over all (img,bin) of -H*log2(H),
// no per-image intermediate is needed. 1024 threads = 4 image-groups x 256
// bins; group g handles images g, g+4, ... Each thread sums the 64 block
// histograms for its (img,bin), adds the entropy term, then one block-wide
// reduction. out = sign * total / IMG_B.
// ---------------------------------------------------------------------------
__global__ __launch_bounds__(1024)
void ie_entropy_kernel(const unsigned* __restrict__ ws, const int* __restrict__ sign,
                       float* __restrict__ out) {
    const int tid = threadIdx.x;
    const int bin = tid & (NBINS - 1);
    const int grp = tid >> 8;            // 0..3
    const float Nf = (float)IMG_HW;
    float acc = 0.0f;

    for (int img = grp; img < IMG_B; img += 4) {
        const unsigned* p = ws + (size_t)img * BPI * NBINS + bin;
        unsigned c = 0;
#pragma unroll 8
        for (int b = 0; b < BPI; ++b) c += p[(size_t)b * NBINS];
        if (c >= 1u) {
            float H = (float)c / Nf;
            acc += -H * log2f(H);
        }
    }

    __shared__ float red[16];
#pragma unroll
    for (int off = 32; off > 0; off >>= 1)
        acc += __shfl_down(acc, off, 64);
    if ((tid & 63) == 0) red[tid >> 6] = acc;
    __syncthreads();
    if (tid == 0) {
        float tot = 0.0f;
#pragma unroll
        for (int w = 0; w < 16; ++w) tot += red[w];
        out[0] = (float)sign[0] * (tot / (float)IMG_B);
    }
}

extern "C" void kernel_launch(void* const* d_in, const int* in_sizes, int n_in,
                              void* d_out, int out_size, void* d_ws, size_t ws_size,
                              hipStream_t stream) {
    const float* x  = (const float*)d_in[0];
    const int* sign = (const int*)d_in[1];
    float* out      = (float*)d_out;
    unsigned* ws    = (unsigned*)d_ws;   // needs IMG_B*BPI*NBINS*4 = 2 MB scratch

    ie_hist_kernel<<<IMG_B * BPI, NTHREADS, 0, stream>>>(x, ws);
    ie_entropy_kernel<<<1, 1024, 0, stream>>>(ws, sign, out);
}

// Round 3
// 148.909 us; speedup vs baseline: 1.4595x; 1.1126x over previous
//
#include <hip/hip_runtime.h>

#define IMG_B 32
#define IMG_HW (512 * 512)
#define NBINS 256
#define BPI 64                       // blocks per image
#define NTHREADS 256
#define CHUNK (IMG_HW / BPI)         // 4096 pixels per block
#define NWAVES (NTHREADS / 64)

// ---------------------------------------------------------------------------
// Kernel 1: per-block 256-bin count histogram. Counts only — the reference's
// H = S/(pixel*N) with pixel = detach(S/cnt) equals cnt/N to ~1 ulp, and the
// bin-0 "+N" offset is dead (y >= 0.0625 -> idx >= 16 -> cnt[0] == 0 always).
// Per-wave privatized LDS uint histograms (native ds_add_u32, no CAS loop),
// block-reduce, plain coalesced store to ws[blk*256 + bin]. No global atomics.
// Grid: IMG_B*BPI = 2048 blocks x 256 thr = 8 blocks/CU = 32 waves/CU (max).
// ---------------------------------------------------------------------------
__global__ __launch_bounds__(NTHREADS)
void ie_hist_kernel(const float* __restrict__ x, unsigned* __restrict__ ws) {
    __shared__ unsigned h[NWAVES][NBINS];

    const int tid  = threadIdx.x;
    const int wave = tid >> 6;
    const int blk  = blockIdx.x;
    const int img  = blk / BPI;
    const int part = blk % BPI;

    for (int i = tid; i < NWAVES * NBINS; i += NTHREADS)
        (&h[0][0])[i] = 0u;
    __syncthreads();

    const float* base = x + (size_t)img * 3u * IMG_HW + (size_t)part * CHUNK;
    const float4* r4 = (const float4*)(base);
    const float4* g4 = (const float4*)(base + IMG_HW);
    const float4* b4 = (const float4*)(base + 2 * IMG_HW);

    const float interval = 1.0f / 255.0f;
    const float eps = 0.5f * interval;

    const int nvec = CHUNK / 4;  // 1024 float4 per channel
    for (int i = tid; i < nvec; i += NTHREADS) {
        float4 r = r4[i];
        float4 g = g4[i];
        float4 b = b4[i];
        float ys[4];
        ys[0] = 0.257f * r.x + 0.564f * g.x + 0.098f * b.x + 0.0625f;
        ys[1] = 0.257f * r.y + 0.564f * g.y + 0.098f * b.y + 0.0625f;
        ys[2] = 0.257f * r.z + 0.564f * g.z + 0.098f * b.z + 0.0625f;
        ys[3] = 0.257f * r.w + 0.564f * g.w + 0.098f * b.w + 0.0625f;
#pragma unroll
        for (int k = 0; k < 4; ++k) {
            float y = ys[k];
            float fidx = rintf(y * 255.0f);     // round-half-to-even == jnp.round
            int idx = (int)fidx;
            float v = fidx * interval;
            bool inb = (y > v - eps) && (y < v + eps) && (idx >= 0) && (idx <= NBINS - 1);
            if (inb) atomicAdd(&h[wave][idx], 1u);
        }
    }
    __syncthreads();

    unsigned c = 0;
#pragma unroll
    for (int w = 0; w < NWAVES; ++w) c += h[w][tid];
    ws[(size_t)blk * NBINS + tid] = c;
}

// ---------------------------------------------------------------------------
// Kernel 2: entropy. One block per image (32 blocks x 256 thr). Thread t sums
// the 64 block-histogram entries for bin t (coalesced: wave reads consecutive
// bins), computes -H*log2(H), block-reduces, then a single device-scope
// atomicAdd of sign*ent/IMG_B into out[0] (zeroed by memset before launch).
// ---------------------------------------------------------------------------
__global__ __launch_bounds__(NTHREADS)
void ie_entropy_kernel(const unsigned* __restrict__ ws, const int* __restrict__ sign,
                       float* __restrict__ out) {
    const int tid = threadIdx.x;
    const int img = blockIdx.x;
    const float Nf = (float)IMG_HW;

    const unsigned* p = ws + (size_t)img * BPI * NBINS + tid;
    unsigned c = 0;
#pragma unroll 8
    for (int b = 0; b < BPI; ++b) c += p[(size_t)b * NBINS];

    float acc = 0.0f;
    if (c >= 1u) {
        float H = (float)c / Nf;
        acc = -H * log2f(H);
    }

    __shared__ float red[NWAVES];
#pragma unroll
    for (int off = 32; off > 0; off >>= 1)
        acc += __shfl_down(acc, off, 64);
    if ((tid & 63) == 0) red[tid >> 6] = acc;
    __syncthreads();
    if (tid == 0) {
        float tot = 0.0f;
#pragma unroll
        for (int w = 0; w < NWAVES; ++w) tot += red[w];
        atomicAdd(out, (float)sign[0] * (tot / (float)IMG_B));
    }
}

extern "C" void kernel_launch(void* const* d_in, const int* in_sizes, int n_in,
                              void* d_out, int out_size, void* d_ws, size_t ws_size,
                              hipStream_t stream) {
    const float* x  = (const float*)d_in[0];
    const int* sign = (const int*)d_in[1];
    float* out      = (float*)d_out;
    unsigned* ws    = (unsigned*)d_ws;   // needs IMG_B*BPI*NBINS*4 = 2 MB scratch

    hipMemsetAsync(d_out, 0, sizeof(float), stream);   // out accumulated via atomicAdd
    ie_hist_kernel<<<IMG_B * BPI, NTHREADS, 0, stream>>>(x, ws);
    ie_entropy_kernel<<<IMG_B, NTHREADS, 0, stream>>>(ws, sign, out);
}